// Round 4
// baseline (302.479 us; speedup 1.0000x reference)
//
#include <hip/hip_runtime.h>
#include <hip/hip_bf16.h>
#include <math.h>

// NetVLAD: B=16, H=W=56 (HW=3136), D=512, K=32, fp32.
// Round 4:
//   Diagnosis R3: k_assign 94us at VALUBusy 13.5% == pure-FMA issue time ->
//   87% stalled on in-loop SMEM s_loads of Wc (SMEM is out-of-order, forcing
//   lgkmcnt(0) FULL drains that also flush ds_reads). k_ax ~85us: barrier-
//   bracketed global staging latency, no prefetch, 2 blocks/CU.
//   Fixes:
//   K1: Wc chunk staged to LDS (in-order ds_read, partial lgkm waits) +
//       register prefetch of next x/Wc chunk across the barrier.
//   K2: register prefetch of next chunk; SPLITS 64 if ws allows (4 blocks/CU).
//   K3: runtime split count.

#define BATCH 16
#define HW    3136
#define DIM   512
#define KCL   32

__device__ __forceinline__ void atomAddF(float* p, float v) {
    unsafeAtomicAdd(p, v);   // global_atomic_add_f32
}

// ---------------- K1: assignment + softmax ----------------
// grid (49, 16), block 256 = 4 waves. Wave wv owns clusters [wv*8, wv*8+8);
// lane = position in the 64-pos tile. D chunks of 64; x AND Wc chunk in LDS;
// next chunk prefetched into VGPRs during compute.
__global__ __launch_bounds__(256) void k_assign(const float* __restrict__ x,
                                                const float* __restrict__ Wc,
                                                float* __restrict__ a,
                                                float* __restrict__ a_sum) {
    __shared__ float xs[64 * 68];    // 17.4 KB; stride 68 -> b128 conflict-free
    __shared__ float wcs[64 * 32];   // 8 KB, rows d, cols k (uniform reads)
    __shared__ float red[4][64];
    const int t    = threadIdx.x;
    const int lane = t & 63;
    const int wv   = t >> 6;
    const int k0   = wv * 8;
    const int b    = blockIdx.y;
    const int pos0 = blockIdx.x * 64;        // 49*64 == 3136

    // staging coords (fixed per thread)
    const int sp  = t >> 4;          // x: pos row 0..15 (x4 iters -> 64)
    const int sc4 = (t & 15) * 4;    // x: col 0..60

    float4 px[4], pw[2];
    {   // preload chunk dc=0
#pragma unroll
        for (int i = 0; i < 4; ++i)
            px[i] = *(const float4*)(x + ((size_t)(b * HW + pos0 + i * 16 + sp) * DIM + sc4));
#pragma unroll
        for (int i = 0; i < 2; ++i)
            pw[i] = *(const float4*)(Wc + (size_t)(i * 256 + t) * 4);
    }

    float acc[8];
#pragma unroll
    for (int j = 0; j < 8; ++j) acc[j] = 0.f;

    for (int dc = 0; dc < DIM; dc += 64) {
        __syncthreads();             // LDS consumers of previous chunk done
#pragma unroll
        for (int i = 0; i < 4; ++i)
            *(float4*)&xs[(i * 16 + sp) * 68 + sc4] = px[i];
#pragma unroll
        for (int i = 0; i < 2; ++i)
            *(float4*)&wcs[(i * 256 + t) * 4] = pw[i];
        __syncthreads();             // chunk visible
        const int dn = dc + 64;
        if (dn < DIM) {              // prefetch next chunk (vmcnt waited next iter)
#pragma unroll
            for (int i = 0; i < 4; ++i)
                px[i] = *(const float4*)(x + ((size_t)(b * HW + pos0 + i * 16 + sp) * DIM + dn + sc4));
#pragma unroll
            for (int i = 0; i < 2; ++i)
                pw[i] = *(const float4*)(Wc + (size_t)dn * KCL + (size_t)(i * 256 + t) * 4);
        }
#pragma unroll
        for (int q = 0; q < 16; ++q) {
            float4 xq = *(const float4*)&xs[lane * 68 + q * 4];
            float xv[4] = {xq.x, xq.y, xq.z, xq.w};
#pragma unroll
            for (int i = 0; i < 4; ++i) {
                const float* wr = &wcs[(q * 4 + i) * KCL + k0];
                float4 w0 = *(const float4*)wr;
                float4 w1 = *(const float4*)(wr + 4);
                acc[0] = fmaf(xv[i], w0.x, acc[0]);
                acc[1] = fmaf(xv[i], w0.y, acc[1]);
                acc[2] = fmaf(xv[i], w0.z, acc[2]);
                acc[3] = fmaf(xv[i], w0.w, acc[3]);
                acc[4] = fmaf(xv[i], w1.x, acc[4]);
                acc[5] = fmaf(xv[i], w1.y, acc[5]);
                acc[6] = fmaf(xv[i], w1.z, acc[6]);
                acc[7] = fmaf(xv[i], w1.w, acc[7]);
            }
        }
    }

    // ---- softmax over 32 k spread across 4 waves (same lane) ----
    float m8 = acc[0];
#pragma unroll
    for (int j = 1; j < 8; ++j) m8 = fmaxf(m8, acc[j]);
    red[wv][lane] = m8;
    __syncthreads();                 // also guards xs reuse below
    float m = fmaxf(fmaxf(red[0][lane], red[1][lane]), fmaxf(red[2][lane], red[3][lane]));
    __syncthreads();
    float s8 = 0.f;
#pragma unroll
    for (int j = 0; j < 8; ++j) { acc[j] = __expf(acc[j] - m); s8 += acc[j]; }
    red[wv][lane] = s8;
    __syncthreads();
    float inv = 1.f / (red[0][lane] + red[1][lane] + red[2][lane] + red[3][lane]);
#pragma unroll
    for (int j = 0; j < 8; ++j) acc[j] *= inv;

    // ---- repack through LDS (reuse xs) for coalesced a stores ----
    float* as_ = xs;                 // as_[pos][k], stride 36
    *(float4*)&as_[lane * 36 + k0]     = make_float4(acc[0], acc[1], acc[2], acc[3]);
    *(float4*)&as_[lane * 36 + k0 + 4] = make_float4(acc[4], acc[5], acc[6], acc[7]);

    // ---- a_sum: butterfly over lanes, 8 atomics per wave ----
#pragma unroll
    for (int j = 0; j < 8; ++j) {
        float v = acc[j];
        v += __shfl_xor(v, 1);  v += __shfl_xor(v, 2);  v += __shfl_xor(v, 4);
        v += __shfl_xor(v, 8);  v += __shfl_xor(v, 16); v += __shfl_xor(v, 32);
        acc[j] = v;
    }
    if (lane == 0) {
#pragma unroll
        for (int j = 0; j < 8; ++j) atomAddF(&a_sum[b * KCL + k0 + j], acc[j]);
    }

    __syncthreads();
#pragma unroll
    for (int r = 0; r < 2; ++r) {
        int idx = r * 256 + t;
        int pos = idx >> 3;
        int c4 = (idx & 7) * 4;
        float4 v = *(const float4*)&as_[pos * 36 + c4];
        *(float4*)(a + ((size_t)(b * HW + pos0 + pos) * KCL + c4)) = v;
    }
}

// ---------------- K2: ax GEMM (split-K over hw, private slabs, prefetch) ----
// grid (spl, 16), block 256. 224 chunks of 14 positions; split s handles
// chunks {s, s+spl, ...}. Next chunk prefetched into VGPRs during compute.
__global__ __launch_bounds__(256) void k_ax(const float* __restrict__ x,
                                            const float* __restrict__ a,
                                            float* __restrict__ vpart, int spl) {
    __shared__ float xs[14 * 512];   // 28 KB
    __shared__ float as_[14 * 32];   // 1.75 KB
    const int t = threadIdx.x;
    const int b = blockIdx.y;
    const int s = blockIdx.x;

    const int d0 = (t >> 2) * 8;
    const int k0 = (t & 3) * 8;
    // staging coords
    const int spos = t >> 7;         // +2 per iter (7 iters of 256 -> 14 rows... )
    // x staging: f = i*256+t -> pos=f>>7, c4=(f&127)*4
    float4 px[7], pa;

    // preload first chunk
    {
        const int pos0 = s * 14;
#pragma unroll
        for (int i = 0; i < 7; ++i) {
            int f = i * 256 + t;
            int pos = f >> 7, c4 = (f & 127) * 4;
            px[i] = *(const float4*)(x + ((size_t)(b * HW + pos0 + pos) * DIM + c4));
        }
        if (t < 112)
            pa = *(const float4*)(a + ((size_t)(b * HW + pos0 + (t >> 3)) * KCL + (t & 7) * 4));
    }
    (void)spos;

    float acc[8][8];
#pragma unroll
    for (int i = 0; i < 8; ++i)
#pragma unroll
        for (int j = 0; j < 8; ++j) acc[i][j] = 0.f;

    for (int chunk = s; chunk < 224; chunk += spl) {
        __syncthreads();
#pragma unroll
        for (int i = 0; i < 7; ++i) {
            int f = i * 256 + t;
            *(float4*)&xs[(f >> 7) * 512 + (f & 127) * 4] = px[i];
        }
        if (t < 112)
            *(float4*)&as_[(t >> 3) * 32 + (t & 7) * 4] = pa;
        __syncthreads();
        const int next = chunk + spl;
        if (next < 224) {            // prefetch (vmcnt waited at next ds_write)
            const int pos0 = next * 14;
#pragma unroll
            for (int i = 0; i < 7; ++i) {
                int f = i * 256 + t;
                int pos = f >> 7, c4 = (f & 127) * 4;
                px[i] = *(const float4*)(x + ((size_t)(b * HW + pos0 + pos) * DIM + c4));
            }
            if (t < 112)
                pa = *(const float4*)(a + ((size_t)(b * HW + pos0 + (t >> 3)) * KCL + (t & 7) * 4));
        }
#pragma unroll 2
        for (int p = 0; p < 14; ++p) {
            float4 xA = *(const float4*)&xs[p * 512 + d0];
            float4 xB = *(const float4*)&xs[p * 512 + d0 + 4];
            float4 aA = *(const float4*)&as_[p * 32 + k0];
            float4 aB = *(const float4*)&as_[p * 32 + k0 + 4];
            float xv[8] = {xA.x, xA.y, xA.z, xA.w, xB.x, xB.y, xB.z, xB.w};
            float av[8] = {aA.x, aA.y, aA.z, aA.w, aB.x, aB.y, aB.z, aB.w};
#pragma unroll
            for (int i = 0; i < 8; ++i)
#pragma unroll
                for (int j = 0; j < 8; ++j)
                    acc[i][j] = fmaf(xv[i], av[j], acc[i][j]);
        }
    }
    float* vp = vpart + ((size_t)s * BATCH * DIM + (size_t)b * DIM) * KCL;
#pragma unroll
    for (int i = 0; i < 8; ++i) {
        float* row = vp + (size_t)(d0 + i) * KCL + k0;
        *(float4*)(row)     = make_float4(acc[i][0], acc[i][1], acc[i][2], acc[i][3]);
        *(float4*)(row + 4) = make_float4(acc[i][4], acc[i][5], acc[i][6], acc[i][7]);
    }
}

// ---------------- K3: split-reduce + C*a_sum + intra-normalize ----------------
__global__ __launch_bounds__(256) void k_norm1(const float* __restrict__ vpart,
                                               const float* __restrict__ a_sum,
                                               const float* __restrict__ Cc,
                                               float* __restrict__ out,
                                               float* __restrict__ ssq, int spl) {
    const int t = threadIdx.x;
    const int row = blockIdx.x * 32 + (t >> 3);
    const int c = (t & 7) * 4;
    const int b = row >> 9;
    const int d = row & 511;

    float4 sum = make_float4(0.f, 0.f, 0.f, 0.f);
    for (int s = 0; s < spl; ++s) {
        float4 p = *(const float4*)(vpart + (((size_t)s * BATCH * DIM + row) * KCL + c));
        sum.x += p.x; sum.y += p.y; sum.z += p.z; sum.w += p.w;
    }
    float4 cc = *(const float4*)(Cc + d * KCL + c);
    float4 as = *(const float4*)(a_sum + b * KCL + c);
    float4 v;
    v.x = sum.x + cc.x * as.x;
    v.y = sum.y + cc.y * as.y;
    v.z = sum.z + cc.z * as.z;
    v.w = sum.w + cc.w * as.w;

    float part = v.x * v.x + v.y * v.y + v.z * v.z + v.w * v.w;
    float ss = part;
    ss += __shfl_xor(ss, 1, 8);
    ss += __shfl_xor(ss, 2, 8);
    ss += __shfl_xor(ss, 4, 8);
    float inv = 1.f / fmaxf(sqrtf(ss), 1e-12f);
    v.x *= inv; v.y *= inv; v.z *= inv; v.w *= inv;
    *(float4*)(out + (size_t)row * KCL + c) = v;

    float bs = part * inv * inv;
    for (int off = 32; off > 0; off >>= 1) bs += __shfl_down(bs, off, 64);
    __shared__ float red[4];
    if ((t & 63) == 0) red[t >> 6] = bs;
    __syncthreads();
    if (t == 0) atomAddF(&ssq[b], red[0] + red[1] + red[2] + red[3]);
}

// ---------------- K4: final global L2 normalize ----------------
__global__ __launch_bounds__(256) void k_norm2(float* __restrict__ out,
                                               const float* __restrict__ ssq) {
    const int i4 = blockIdx.x * 256 + threadIdx.x;
    const int b = i4 >> 12;
    float inv = 1.f / fmaxf(sqrtf(ssq[b]), 1e-12f);
    float4 v = *(float4*)(out + (size_t)i4 * 4);
    v.x *= inv; v.y *= inv; v.z *= inv; v.w *= inv;
    *(float4*)(out + (size_t)i4 * 4) = v;
}

extern "C" void kernel_launch(void* const* d_in, const int* in_sizes, int n_in,
                              void* d_out, int out_size, void* d_ws, size_t ws_size,
                              hipStream_t stream) {
    const float* x  = (const float*)d_in[0];
    const float* Wc = (const float*)d_in[1];
    const float* Cc = (const float*)d_in[2];
    float* out = (float*)d_out;

    // splits: 64 if workspace allows (4 blocks/CU), else 32
    const size_t A_BYTES = 6422528;                       // a: N*K*4
    const size_t VP64 = (size_t)64 * BATCH * DIM * KCL * 4;  // 67,108,864
    const size_t VP32 = (size_t)32 * BATCH * DIM * KCL * 4;  // 33,554,432
    const int spl = (ws_size >= A_BYTES + VP64 + 2048 + 64) ? 64 : 32;
    const size_t vpb = (spl == 64) ? VP64 : VP32;

    char* ws = (char*)d_ws;
    float* a     = (float*)ws;
    float* vpart = (float*)(ws + A_BYTES);
    float* a_sum = (float*)(ws + A_BYTES + vpb);
    float* ssq   = (float*)(ws + A_BYTES + vpb + 2048);

    hipMemsetAsync(a_sum, 0, 2048 + 64, stream);

    k_assign<<<dim3(49, 16), 256, 0, stream>>>(x, Wc, a, a_sum);
    k_ax    <<<dim3(spl, 16), 256, 0, stream>>>(x, a, vpart, spl);
    k_norm1 <<<256, 256, 0, stream>>>(vpart, a_sum, Cc, out, ssq, spl);
    k_norm2 <<<256, 256, 0, stream>>>(out, ssq);
}

// Round 5
// 294.802 us; speedup vs baseline: 1.0260x; 1.0260x over previous
//
#include <hip/hip_runtime.h>
#include <hip/hip_bf16.h>
#include <math.h>

// NetVLAD: B=16, H=W=56 (HW=3136), D=512, K=32, fp32.
// Round 5: both GEMMs were latency-bound at ~3 blocks/CU (grid-limited);
// R4 proved operand-path tweaks don't fix that. This round raises waves/CU
// structurally by splitting the reduction dim across blocks:
//   K1 k_s    : s-partial GEMM, d-split 4 -> grid 3136 blocks (~32 waves/CU),
//               R3's SMEM-Wc inner loop (readfirstlane restored).
//   K2 k_soft : sum 4 s-partials + softmax -> a, a_sum (streaming pass).
//   K3 k_ax   : unchanged 8x8-tile GEMM, spl=64 (ws-gated) -> 4 blocks/CU.
//   K4 k_norm1: split-reduce + C*a_sum + intra-normalize.
//   K5 k_norm2: global L2 normalize.

#define BATCH 16
#define HW    3136
#define DIM   512
#define KCL   32

__device__ __forceinline__ void atomAddF(float* p, float v) {
    unsafeAtomicAdd(p, v);   // global_atomic_add_f32
}

// ---------------- K1: s-partial GEMM ----------------
// grid (49, 4, 16), block 256 = 4 waves. Block: 64 positions x 128 d's.
// Wave wv owns clusters [wv*8, wv*8+8); lane = position. 2 d-chunks of 64.
// Wc read via wave-uniform SMEM s_loads (R3-proven); x tile in LDS.
__global__ __launch_bounds__(256) void k_s(const float* __restrict__ x,
                                           const float* __restrict__ Wc,
                                           float* __restrict__ spart) {
    __shared__ float xs[64 * 68];    // 17.4 KB
    const int t    = threadIdx.x;
    const int lane = t & 63;
    const int wv   = t >> 6;
    const int k0   = __builtin_amdgcn_readfirstlane(wv * 8);  // force SGPR
    const int b    = blockIdx.z;
    const int ds   = blockIdx.y;             // d-split 0..3
    const int pos0 = blockIdx.x * 64;        // 49*64 == 3136
    const int d0   = ds * 128;

    const int sp  = t >> 4;          // staging: pos row 0..15 (x4)
    const int sc4 = (t & 15) * 4;    // staging: col 0..60

    float4 px[4];
#pragma unroll
    for (int i = 0; i < 4; ++i)
        px[i] = *(const float4*)(x + ((size_t)(b * HW + pos0 + i * 16 + sp) * DIM + d0 + sc4));

    float acc[8];
#pragma unroll
    for (int j = 0; j < 8; ++j) acc[j] = 0.f;

#pragma unroll
    for (int c = 0; c < 2; ++c) {
        __syncthreads();
#pragma unroll
        for (int i = 0; i < 4; ++i)
            *(float4*)&xs[(i * 16 + sp) * 68 + sc4] = px[i];
        __syncthreads();
        if (c == 0) {                // prefetch chunk 1 during chunk 0 compute
#pragma unroll
            for (int i = 0; i < 4; ++i)
                px[i] = *(const float4*)(x + ((size_t)(b * HW + pos0 + i * 16 + sp) * DIM + d0 + 64 + sc4));
        }
        const float* wrow = Wc + (size_t)(d0 + c * 64) * KCL;  // uniform -> s_load
#pragma unroll
        for (int q = 0; q < 16; ++q) {
            float4 xq = *(const float4*)&xs[lane * 68 + q * 4];
            float xv[4] = {xq.x, xq.y, xq.z, xq.w};
#pragma unroll
            for (int i = 0; i < 4; ++i) {
#pragma unroll
                for (int j = 0; j < 8; ++j)
                    acc[j] = fmaf(xv[i], wrow[(q * 4 + i) * KCL + k0 + j], acc[j]);
            }
        }
    }

    // repack through LDS (reuse xs) for coalesced partial stores
    __syncthreads();
    float* as_ = xs;                 // as_[pos][k], stride 36
    *(float4*)&as_[lane * 36 + k0]     = make_float4(acc[0], acc[1], acc[2], acc[3]);
    *(float4*)&as_[lane * 36 + k0 + 4] = make_float4(acc[4], acc[5], acc[6], acc[7]);
    __syncthreads();
    float* so = spart + ((size_t)ds * BATCH * HW + (size_t)b * HW + pos0) * KCL;
#pragma unroll
    for (int r = 0; r < 2; ++r) {
        int idx = r * 256 + t;       // 0..511
        int pos = idx >> 3;
        int c4 = (idx & 7) * 4;
        *(float4*)(so + (size_t)pos * KCL + c4) = *(const float4*)&as_[pos * 36 + c4];
    }
}

// ---------------- K2: sum partials + softmax ----------------
// grid 196, block 256: thread = one position (196*256 == 50176 == B*HW).
__global__ __launch_bounds__(256) void k_soft(const float* __restrict__ spart,
                                              float* __restrict__ a,
                                              float* __restrict__ a_sum) {
    const int n = blockIdx.x * 256 + threadIdx.x;   // 0..50175
    const int b = n / HW;            // 3136 % 64 == 0 -> wave-uniform
    const int lane = threadIdx.x & 63;

    float s[KCL];
#pragma unroll
    for (int k4 = 0; k4 < KCL; k4 += 4) {
        float4 v = *(const float4*)(spart + ((size_t)n * KCL + k4));
        s[k4] = v.x; s[k4 + 1] = v.y; s[k4 + 2] = v.z; s[k4 + 3] = v.w;
    }
#pragma unroll
    for (int ds = 1; ds < 4; ++ds) {
        const float* sl = spart + (size_t)ds * BATCH * HW * KCL + (size_t)n * KCL;
#pragma unroll
        for (int k4 = 0; k4 < KCL; k4 += 4) {
            float4 v = *(const float4*)(sl + k4);
            s[k4] += v.x; s[k4 + 1] += v.y; s[k4 + 2] += v.z; s[k4 + 3] += v.w;
        }
    }

    float m = s[0];
#pragma unroll
    for (int k = 1; k < KCL; ++k) m = fmaxf(m, s[k]);
    float sum = 0.f;
#pragma unroll
    for (int k = 0; k < KCL; ++k) { s[k] = __expf(s[k] - m); sum += s[k]; }
    float inv = 1.f / sum;
#pragma unroll
    for (int k = 0; k < KCL; ++k) s[k] *= inv;

#pragma unroll
    for (int k4 = 0; k4 < KCL; k4 += 4)
        *(float4*)(a + ((size_t)n * KCL + k4)) = make_float4(s[k4], s[k4 + 1], s[k4 + 2], s[k4 + 3]);

    // a_sum: butterfly over 64 lanes (positions), 32 atomics per wave
#pragma unroll
    for (int k = 0; k < KCL; ++k) {
        float v = s[k];
        v += __shfl_xor(v, 1);  v += __shfl_xor(v, 2);  v += __shfl_xor(v, 4);
        v += __shfl_xor(v, 8);  v += __shfl_xor(v, 16); v += __shfl_xor(v, 32);
        s[k] = v;
    }
    if (lane == 0) {
#pragma unroll
        for (int k = 0; k < KCL; ++k) atomAddF(&a_sum[b * KCL + k], s[k]);
    }
}

// ---------------- K3: ax GEMM (split-K over hw, private slabs, prefetch) ----
// grid (spl, 16), block 256. 224 chunks of 14 positions; split s handles
// chunks {s, s+spl, ...}. Next chunk prefetched into VGPRs during compute.
__global__ __launch_bounds__(256) void k_ax(const float* __restrict__ x,
                                            const float* __restrict__ a,
                                            float* __restrict__ vpart, int spl) {
    __shared__ float xs[14 * 512];   // 28 KB
    __shared__ float as_[14 * 32];   // 1.75 KB
    const int t = threadIdx.x;
    const int b = blockIdx.y;
    const int s = blockIdx.x;

    const int d0 = (t >> 2) * 8;
    const int k0 = (t & 3) * 8;
    float4 px[7], pa;

    {
        const int pos0 = s * 14;
#pragma unroll
        for (int i = 0; i < 7; ++i) {
            int f = i * 256 + t;
            px[i] = *(const float4*)(x + ((size_t)(b * HW + pos0 + (f >> 7)) * DIM + (f & 127) * 4));
        }
        if (t < 112)
            pa = *(const float4*)(a + ((size_t)(b * HW + pos0 + (t >> 3)) * KCL + (t & 7) * 4));
    }

    float acc[8][8];
#pragma unroll
    for (int i = 0; i < 8; ++i)
#pragma unroll
        for (int j = 0; j < 8; ++j) acc[i][j] = 0.f;

    for (int chunk = s; chunk < 224; chunk += spl) {
        __syncthreads();
#pragma unroll
        for (int i = 0; i < 7; ++i) {
            int f = i * 256 + t;
            *(float4*)&xs[(f >> 7) * 512 + (f & 127) * 4] = px[i];
        }
        if (t < 112)
            *(float4*)&as_[(t >> 3) * 32 + (t & 7) * 4] = pa;
        __syncthreads();
        const int next = chunk + spl;
        if (next < 224) {
            const int pos0 = next * 14;
#pragma unroll
            for (int i = 0; i < 7; ++i) {
                int f = i * 256 + t;
                px[i] = *(const float4*)(x + ((size_t)(b * HW + pos0 + (f >> 7)) * DIM + (f & 127) * 4));
            }
            if (t < 112)
                pa = *(const float4*)(a + ((size_t)(b * HW + pos0 + (t >> 3)) * KCL + (t & 7) * 4));
        }
#pragma unroll 2
        for (int p = 0; p < 14; ++p) {
            float4 xA = *(const float4*)&xs[p * 512 + d0];
            float4 xB = *(const float4*)&xs[p * 512 + d0 + 4];
            float4 aA = *(const float4*)&as_[p * 32 + k0];
            float4 aB = *(const float4*)&as_[p * 32 + k0 + 4];
            float xv[8] = {xA.x, xA.y, xA.z, xA.w, xB.x, xB.y, xB.z, xB.w};
            float av[8] = {aA.x, aA.y, aA.z, aA.w, aB.x, aB.y, aB.z, aB.w};
#pragma unroll
            for (int i = 0; i < 8; ++i)
#pragma unroll
                for (int j = 0; j < 8; ++j)
                    acc[i][j] = fmaf(xv[i], av[j], acc[i][j]);
        }
    }
    float* vp = vpart + ((size_t)s * BATCH * DIM + (size_t)b * DIM) * KCL;
#pragma unroll
    for (int i = 0; i < 8; ++i) {
        float* row = vp + (size_t)(d0 + i) * KCL + k0;
        *(float4*)(row)     = make_float4(acc[i][0], acc[i][1], acc[i][2], acc[i][3]);
        *(float4*)(row + 4) = make_float4(acc[i][4], acc[i][5], acc[i][6], acc[i][7]);
    }
}

// ---------------- K4: split-reduce + C*a_sum + intra-normalize ----------------
__global__ __launch_bounds__(256) void k_norm1(const float* __restrict__ vpart,
                                               const float* __restrict__ a_sum,
                                               const float* __restrict__ Cc,
                                               float* __restrict__ out,
                                               float* __restrict__ ssq, int spl) {
    const int t = threadIdx.x;
    const int row = blockIdx.x * 32 + (t >> 3);
    const int c = (t & 7) * 4;
    const int b = row >> 9;
    const int d = row & 511;

    float4 sum = make_float4(0.f, 0.f, 0.f, 0.f);
    for (int s = 0; s < spl; ++s) {
        float4 p = *(const float4*)(vpart + (((size_t)s * BATCH * DIM + row) * KCL + c));
        sum.x += p.x; sum.y += p.y; sum.z += p.z; sum.w += p.w;
    }
    float4 cc = *(const float4*)(Cc + d * KCL + c);
    float4 as = *(const float4*)(a_sum + b * KCL + c);
    float4 v;
    v.x = sum.x + cc.x * as.x;
    v.y = sum.y + cc.y * as.y;
    v.z = sum.z + cc.z * as.z;
    v.w = sum.w + cc.w * as.w;

    float part = v.x * v.x + v.y * v.y + v.z * v.z + v.w * v.w;
    float ss = part;
    ss += __shfl_xor(ss, 1, 8);
    ss += __shfl_xor(ss, 2, 8);
    ss += __shfl_xor(ss, 4, 8);
    float inv = 1.f / fmaxf(sqrtf(ss), 1e-12f);
    v.x *= inv; v.y *= inv; v.z *= inv; v.w *= inv;
    *(float4*)(out + (size_t)row * KCL + c) = v;

    float bs = part * inv * inv;
    for (int off = 32; off > 0; off >>= 1) bs += __shfl_down(bs, off, 64);
    __shared__ float red[4];
    if ((t & 63) == 0) red[t >> 6] = bs;
    __syncthreads();
    if (t == 0) atomAddF(&ssq[b], red[0] + red[1] + red[2] + red[3]);
}

// ---------------- K5: final global L2 normalize ----------------
__global__ __launch_bounds__(256) void k_norm2(float* __restrict__ out,
                                               const float* __restrict__ ssq) {
    const int i4 = blockIdx.x * 256 + threadIdx.x;
    const int b = i4 >> 12;
    float inv = 1.f / fmaxf(sqrtf(ssq[b]), 1e-12f);
    float4 v = *(float4*)(out + (size_t)i4 * 4);
    v.x *= inv; v.y *= inv; v.z *= inv; v.w *= inv;
    *(float4*)(out + (size_t)i4 * 4) = v;
}

extern "C" void kernel_launch(void* const* d_in, const int* in_sizes, int n_in,
                              void* d_out, int out_size, void* d_ws, size_t ws_size,
                              hipStream_t stream) {
    const float* x  = (const float*)d_in[0];
    const float* Wc = (const float*)d_in[1];
    const float* Cc = (const float*)d_in[2];
    float* out = (float*)d_out;

    // ws layout: a (6.4 MB) | spart (4x6.4 MB) | vpart (spl MB) | a_sum | ssq
    const size_t A_B   = (size_t)BATCH * HW * KCL * 4;        //  6,422,528
    const size_t SP_B  = 4 * A_B;                             // 25,690,112
    const size_t SLAB  = (size_t)BATCH * DIM * KCL * 4;       //  1,048,576
    const size_t BASE  = A_B + SP_B;

    int spl = 4;
    if      (ws_size >= BASE + 64 * SLAB + 2112) spl = 64;
    else if (ws_size >= BASE + 32 * SLAB + 2112) spl = 32;
    else if (ws_size >= BASE + 16 * SLAB + 2112) spl = 16;
    else if (ws_size >= BASE +  8 * SLAB + 2112) spl = 8;

    char* ws = (char*)d_ws;
    float* a     = (float*)ws;
    float* spart = (float*)(ws + A_B);
    float* vpart = (float*)(ws + BASE);
    float* a_sum = (float*)(ws + BASE + (size_t)spl * SLAB);
    float* ssq   = (float*)(ws + BASE + (size_t)spl * SLAB + 2048);

    hipMemsetAsync(a_sum, 0, 2048 + 64, stream);

    k_s    <<<dim3(49, 4, 16), 256, 0, stream>>>(x, Wc, spart);
    k_soft <<<196, 256, 0, stream>>>(spart, a, a_sum);
    k_ax   <<<dim3(spl, 16), 256, 0, stream>>>(x, a, vpart, spl);
    k_norm1<<<256, 256, 0, stream>>>(vpart, a_sum, Cc, out, ssq, spl);
    k_norm2<<<256, 256, 0, stream>>>(out, ssq);
}